// Round 16
// baseline (221.466 us; speedup 1.0000x reference)
//
#include <hip/hip_runtime.h>

// DivEncLayer — AMPLIFIED ABLATION. r15's per-phase rows were hidden below the
// top-5 cutoff (six ~40us harness fill dispatches). Each phase kernel now
// repeats its body REP times so every dispatch lands >45us and is visible:
//   P0 x8: staging loop only (loads+cvt+LDS writes+barriers)
//   P1 x6: P0 + ds_read B-frags + 2x MFMA          (acc kept alive)
//   P2 x4: P1 + ELU + sum/ss/dot reduce            (partials kept alive)
//   P3 x2: full r11 kernel (real output; lout rewritten identically per rep)
// Marginals: m0=P0/8, m1=P1/6-m0, m2=P2/4-P1/6, m3=P3/2-P2/4.
// Cross-rep global-load CSE defeated via asm-opaque z=0 in the address
// (compiler must re-issue loads each rep). LDS writes = side effects (no DCE).

typedef __attribute__((ext_vector_type(8))) short short8;    // 8 bf16
typedef __attribute__((ext_vector_type(16))) float f32x16;

#define XS_STRIDE 40   // shorts per staged row (80 B): b128-aligned
#define KEEP(x) asm volatile("" :: "v"(x))

__device__ __forceinline__ short fbits(__bf16 b) { return __builtin_bit_cast(short, b); }

__device__ __forceinline__ float elu1(float v) {
    return v > 0.f ? v : __expf(v) - 1.f;
}

__device__ __forceinline__ short4 cvt4(float4 v) {
    short4 r;
    r.x = fbits((__bf16)v.x); r.y = fbits((__bf16)v.y);
    r.z = fbits((__bf16)v.z); r.w = fbits((__bf16)v.w);
    return r;
}

template<int PHASE, int REP>
__global__ __launch_bounds__(256, 4) void divenc_abl(
    const float* __restrict__ x,      // (16384, 1024)
    const float* __restrict__ W1,     // (128, 8, 32)
    const float* __restrict__ b1,     // (128, 32)
    const float* __restrict__ gamma,  // (128, 32)
    const float* __restrict__ beta,   // (128, 32)
    const float* __restrict__ W2,     // (128, 32)
    const float* __restrict__ b2,     // (128,)
    float* __restrict__ out)          // (16384, 128)  [P<3: unused]
{
    __shared__ short xs[2][64 * XS_STRIDE];   // staged bf16 panels
    __shared__ float lout[256 * 5];           // results, padded stride 5

    const int tid  = threadIdx.x;
    const int w    = tid >> 6;
    const int ln   = tid & 63;
    const int u    = ln & 31;
    const int half = ln >> 5;
    const int qt   = blockIdx.y;      // 0..31
    const int q    = qt * 4 + w;
    const int bx   = blockIdx.x;      // 0..63; band = rows bx*256..+255
    const int band = bx * 256;

    // staging role: 8 threads cover one 128B row; thread t does rows t>>3, +32
    const int srow0 = tid >> 3;
    const int srow1 = srow0 + 32;
    const int schk  = tid & 7;
    const float* xpan = x + qt * 32 + schk * 4;

    // ---- A-frag: lanes<32 = whi (k=0..7), lanes>=32 = wlo (k=8..15) ----
    short8 wfrag;
    #pragma unroll
    for (int j = 0; j < 8; ++j) {
        float f  = W1[q * 256 + j * 32 + u];
        __bf16 h = (__bf16)f;
        wfrag[j] = half ? fbits((__bf16)(f - (float)h)) : fbits(h);
    }

    // ---- params: biasr (MFMA C-in) + g2r in regs, vector loads ----
    f32x16 biasr, g2r;
    float G, C;
    {
        float gs = 0.f, cs = 0.f;
        #pragma unroll
        for (int c = 0; c < 4; ++c) {
            const int ub = q * 32 + 4 * half + 8 * c;
            float4 b1v = *(const float4*)&b1[ub];
            float4 gav = *(const float4*)&gamma[ub];
            float4 w2v = *(const float4*)&W2[ub];
            float4 bev = *(const float4*)&beta[ub];
            #pragma unroll
            for (int j = 0; j < 4; ++j) {
                float g2 = ((const float*)&gav)[j] * ((const float*)&w2v)[j];
                biasr[4 * c + j] = ((const float*)&b1v)[j];
                g2r[4 * c + j]   = g2;
                gs += g2;
                cs += ((const float*)&bev)[j] * ((const float*)&w2v)[j];
            }
        }
        gs += __shfl_xor(gs, 32);
        cs += __shfl_xor(cs, 32);
        G = gs;
        C = cs + b2[q];
    }

    // opaque zero: addresses below depend on rep -> no cross-rep load CSE
    int z = 0;
    asm volatile("" : "+s"(z));

    #pragma unroll 1
    for (int rep = 0; rep < REP; ++rep) {
        const int bandr = band + z * rep;   // == band at runtime

        // ---- prologue: stage iter-0 panel (fully coalesced) ----
        {
            float4 g0 = *(const float4*)(xpan + (size_t)(bandr + srow0) * 1024);
            float4 g1 = *(const float4*)(xpan + (size_t)(bandr + srow1) * 1024);
            *(short4*)&xs[0][srow0 * XS_STRIDE + schk * 4] = cvt4(g0);
            *(short4*)&xs[0][srow1 * XS_STRIDE + schk * 4] = cvt4(g1);
        }
        __syncthreads();

        #pragma unroll 1
        for (int it = 0; it < 4; ++it) {
            const int cur = it & 1;
            const int b0  = it * 64;        // row offset within band

            // issue next panel's coalesced loads early
            float4 g0, g1;
            if (it < 3) {
                g0 = *(const float4*)(xpan + (size_t)(bandr + b0 + 64 + srow0) * 1024);
                g1 = *(const float4*)(xpan + (size_t)(bandr + b0 + 64 + srow1) * 1024);
            }

            if constexpr (PHASE >= 1) {
                // B-frags from staged panel (one b128 each, halves dup)
                short8 xa = *(const short8*)&xs[cur][u * XS_STRIDE + w * 8];
                short8 xb = *(const short8*)&xs[cur][(u + 32) * XS_STRIDE + w * 8];

                f32x16 accA = __builtin_amdgcn_mfma_f32_32x32x16_bf16(wfrag, xa, biasr, 0, 0, 0);
                f32x16 accB = __builtin_amdgcn_mfma_f32_32x32x16_bf16(wfrag, xb, biasr, 0, 0, 0);

                if constexpr (PHASE == 1) {
                    KEEP(accA[0]); KEEP(accA[15]);
                    KEEP(accB[0]); KEEP(accB[15]);
                }

                if constexpr (PHASE >= 2) {
                    // tile A
                    {
                        float sum = 0.f, ss = 0.f, dot = 0.f;
                        #pragma unroll
                        for (int r = 0; r < 16; ++r) {
                            float e = elu1(accA[r]);
                            sum += e;
                            ss  = fmaf(e, e, ss);
                            dot = fmaf(e, g2r[r], dot);
                        }
                        if constexpr (PHASE == 2) {
                            KEEP(sum); KEEP(ss); KEEP(dot);
                        } else {
                            sum += __shfl_xor(sum, 32);
                            ss  += __shfl_xor(ss, 32);
                            dot += __shfl_xor(dot, 32);
                            float mu  = sum * 0.03125f;
                            float var = fmaf(-mu, mu, ss * 0.03125f);
                            float inv = rsqrtf(var + 1e-3f);
                            float res = fmaf(inv, fmaf(-mu, G, dot), C);
                            if (half == 0) lout[(b0 + u) * 5 + w] = res;
                        }
                    }
                    // tile B
                    {
                        float sum = 0.f, ss = 0.f, dot = 0.f;
                        #pragma unroll
                        for (int r = 0; r < 16; ++r) {
                            float e = elu1(accB[r]);
                            sum += e;
                            ss  = fmaf(e, e, ss);
                            dot = fmaf(e, g2r[r], dot);
                        }
                        if constexpr (PHASE == 2) {
                            KEEP(sum); KEEP(ss); KEEP(dot);
                        } else {
                            sum += __shfl_xor(sum, 32);
                            ss  += __shfl_xor(ss, 32);
                            dot += __shfl_xor(dot, 32);
                            float mu  = sum * 0.03125f;
                            float var = fmaf(-mu, mu, ss * 0.03125f);
                            float inv = rsqrtf(var + 1e-3f);
                            float res = fmaf(inv, fmaf(-mu, G, dot), C);
                            if (half == 0) lout[(b0 + 32 + u) * 5 + w] = res;
                        }
                    }
                }
            } else {
                KEEP(wfrag[0]);   // keep setup comparable across phases
            }

            // write next panel, then the iter barrier (identical in all phases)
            if (it < 3) {
                *(short4*)&xs[cur ^ 1][srow0 * XS_STRIDE + schk * 4] = cvt4(g0);
                *(short4*)&xs[cur ^ 1][srow1 * XS_STRIDE + schk * 4] = cvt4(g1);
            }
            __syncthreads();
        }
    }

    if constexpr (PHASE >= 3) {
        // ---- gather/store: 256 rows, one float4 per thread ----
        float4 o;
        o.x = lout[tid * 5 + 0];
        o.y = lout[tid * 5 + 1];
        o.z = lout[tid * 5 + 2];
        o.w = lout[tid * 5 + 3];
        *(float4*)(out + (size_t)(band + tid) * 128 + qt * 4) = o;
    }
}

extern "C" void kernel_launch(void* const* d_in, const int* in_sizes, int n_in,
                              void* d_out, int out_size, void* d_ws, size_t ws_size,
                              hipStream_t stream) {
    const float* x     = (const float*)d_in[0];
    const float* W1    = (const float*)d_in[1];
    const float* b1    = (const float*)d_in[2];
    const float* gamma = (const float*)d_in[3];
    const float* beta  = (const float*)d_in[4];
    const float* W2    = (const float*)d_in[5];
    const float* b2    = (const float*)d_in[6];
    float* out = (float*)d_out;
    float* ws  = (float*)d_ws;   // dummy target for truncated variants

    dim3 grid(64, 32);   // (256-row bands, q-tiles of 4) = 2048 blocks

    // real kernel first (REP=2; writes d_out)
    divenc_abl<3, 2><<<grid, 256, 0, stream>>>(x, W1, b1, gamma, beta, W2, b2, out);
    // amplified ablation probes (write nothing)
    divenc_abl<0, 8><<<grid, 256, 0, stream>>>(x, W1, b1, gamma, beta, W2, b2, ws);
    divenc_abl<1, 6><<<grid, 256, 0, stream>>>(x, W1, b1, gamma, beta, W2, b2, ws);
    divenc_abl<2, 4><<<grid, 256, 0, stream>>>(x, W1, b1, gamma, beta, W2, b2, ws);
}

// Round 17
// 27.682 us; speedup vs baseline: 8.0002x; 8.0002x over previous
//
#include <hip/hip_runtime.h>

// DivEncLayer via MFMA — r11 compute core + COUNTED-WAIT PIPELINED staging.
// Per (b,q): h = elu(x[b,q*8:+8]@W1[q] + b1[q]); LN(h); out = h@W2[q]+b2[q].
// B=16384, Q=128, S=8, U=32.
//
// r16 ablation: staging-alone = 9.8us/pass (34%), additive with compute ->
// the per-iter __syncthreads (drains vmcnt(0)) serializes staging vs compute.
// Fix (T3/T4-lite): 3-deep panel rotation, loads issued 2 iters ahead, and
// raw `s_waitcnt lgkmcnt(0)` + s_barrier instead of __syncthreads -> the
// next panel's loads stay in flight across the barrier (compiler emits
// vmcnt(2) before the ds_write that consumes the older pair).
// Race-safe: panel (it+2)%3's readers finished at barrier it-1.
//
// v_mfma_f32_32x32x16_bf16 mapping (validated r2-r11):
//   A: lane l, reg j -> A[l&31][j + 8*(l>>5)]
//   B: lane l, reg j -> B[j + 8*(l>>5)][l&31]
//   D: lane l, reg r -> row u=(r&3)+8*(r>>2)+4*(l>>5), col b=l&31
// Packed A-frag: lanes<32 = bf16(W1^T) (k<8), lanes>=32 = bf16(W1-hi) (k>=8).
// B-frag: staged bf16 panel row u (halves dup) -> one ds_read_b128.
// D = (whi+wlo)*xhi + b1 (C-in fp32). LN+Dense2 folded:
//   out = rsqrt(var+eps)*(dot(e,g2) - mu*G) + C.
// Block = 4 waves = q-tile; 8 iters x 64 rows = 512-row band; grid (32,32).
// Coalesced float4 staging (8 thr/row), lout gather, float4 stores.

typedef __attribute__((ext_vector_type(8))) short short8;    // 8 bf16
typedef __attribute__((ext_vector_type(16))) float f32x16;

#define XS_STRIDE 40   // shorts per staged row (80 B): b128-aligned, 0-conflict (r11)

__device__ __forceinline__ short fbits(__bf16 b) { return __builtin_bit_cast(short, b); }

__device__ __forceinline__ float elu1(float v) {
    return v > 0.f ? v : __expf(v) - 1.f;
}

__device__ __forceinline__ short4 cvt4(float4 v) {
    short4 r;
    r.x = fbits((__bf16)v.x); r.y = fbits((__bf16)v.y);
    r.z = fbits((__bf16)v.z); r.w = fbits((__bf16)v.w);
    return r;
}

// barrier WITHOUT vmcnt drain: DS visibility only, global loads stay in flight
__device__ __forceinline__ void barrier_ds_only() {
    asm volatile("s_waitcnt lgkmcnt(0)" ::: "memory");
    __builtin_amdgcn_s_barrier();
}

__global__ __launch_bounds__(256, 4) void divenc_mfma(
    const float* __restrict__ x,      // (16384, 1024)
    const float* __restrict__ W1,     // (128, 8, 32)
    const float* __restrict__ b1,     // (128, 32)
    const float* __restrict__ gamma,  // (128, 32)
    const float* __restrict__ beta,   // (128, 32)
    const float* __restrict__ W2,     // (128, 32)
    const float* __restrict__ b2,     // (128,)
    float* __restrict__ out)          // (16384, 128)
{
    __shared__ short xs[3][64 * XS_STRIDE];   // 3-deep staged bf16 panels (5KB each)
    __shared__ float lout[512 * 5];           // results, padded stride 5 (10KB)

    const int tid  = threadIdx.x;
    const int w    = tid >> 6;
    const int ln   = tid & 63;
    const int u    = ln & 31;
    const int half = ln >> 5;
    const int qt   = blockIdx.y;      // 0..31
    const int q    = qt * 4 + w;
    const int bx   = blockIdx.x;      // 0..31; band = rows bx*512..+511
    const int band = bx * 512;

    // staging role: 8 threads cover one 128B row; thread t does rows t>>3, +32
    const int srow0 = tid >> 3;
    const int srow1 = srow0 + 32;
    const int schk  = tid & 7;
    const float* xpan = x + qt * 32 + schk * 4;

    // ---- A-frag: lanes<32 = whi (k=0..7), lanes>=32 = wlo (k=8..15) ----
    short8 wfrag;
    #pragma unroll
    for (int j = 0; j < 8; ++j) {
        float f  = W1[q * 256 + j * 32 + u];
        __bf16 h = (__bf16)f;
        wfrag[j] = half ? fbits((__bf16)(f - (float)h)) : fbits(h);
    }

    // ---- params: biasr (MFMA C-in) + g2r in regs, vector loads ----
    f32x16 biasr, g2r;
    float G, C;
    {
        float gs = 0.f, cs = 0.f;
        #pragma unroll
        for (int c = 0; c < 4; ++c) {
            const int ub = q * 32 + 4 * half + 8 * c;
            float4 b1v = *(const float4*)&b1[ub];
            float4 gav = *(const float4*)&gamma[ub];
            float4 w2v = *(const float4*)&W2[ub];
            float4 bev = *(const float4*)&beta[ub];
            #pragma unroll
            for (int j = 0; j < 4; ++j) {
                float g2 = ((const float*)&gav)[j] * ((const float*)&w2v)[j];
                biasr[4 * c + j] = ((const float*)&b1v)[j];
                g2r[4 * c + j]   = g2;
                gs += g2;
                cs += ((const float*)&bev)[j] * ((const float*)&w2v)[j];
            }
        }
        gs += __shfl_xor(gs, 32);   // halves hold complementary u-sets
        cs += __shfl_xor(cs, 32);
        G = gs;
        C = cs + b2[q];
    }

    // ---- prologue: stage panel 0; issue panel 1's loads (stay in flight) ----
    {
        float4 g0 = *(const float4*)(xpan + (size_t)(band + srow0) * 1024);
        float4 g1 = *(const float4*)(xpan + (size_t)(band + srow1) * 1024);
        *(short4*)&xs[0][srow0 * XS_STRIDE + schk * 4] = cvt4(g0);
        *(short4*)&xs[0][srow1 * XS_STRIDE + schk * 4] = cvt4(g1);
    }
    float4 p0 = *(const float4*)(xpan + (size_t)(band + 64 + srow0) * 1024);
    float4 p1 = *(const float4*)(xpan + (size_t)(band + 64 + srow1) * 1024);
    barrier_ds_only();

    #pragma unroll 1
    for (int it = 0; it < 8; ++it) {
        const int cur = it % 3;
        const int nxt = (it + 1) % 3;
        const int b0  = it * 64;        // row offset within band

        // issue loads for panel it+2 (2 iterations ahead; stay in flight)
        float4 f0, f1;
        if (it < 6) {
            f0 = *(const float4*)(xpan + (size_t)(band + b0 + 128 + srow0) * 1024);
            f1 = *(const float4*)(xpan + (size_t)(band + b0 + 128 + srow1) * 1024);
        }

        // ---- compute on panel cur (bit-identical to r11) ----
        short8 xa = *(const short8*)&xs[cur][u * XS_STRIDE + w * 8];
        short8 xb = *(const short8*)&xs[cur][(u + 32) * XS_STRIDE + w * 8];

        f32x16 accA = __builtin_amdgcn_mfma_f32_32x32x16_bf16(wfrag, xa, biasr, 0, 0, 0);
        f32x16 accB = __builtin_amdgcn_mfma_f32_32x32x16_bf16(wfrag, xb, biasr, 0, 0, 0);

        {
            float sum = 0.f, ss = 0.f, dot = 0.f;
            #pragma unroll
            for (int r = 0; r < 16; ++r) {
                float e = elu1(accA[r]);
                sum += e;
                ss  = fmaf(e, e, ss);
                dot = fmaf(e, g2r[r], dot);
            }
            sum += __shfl_xor(sum, 32);
            ss  += __shfl_xor(ss, 32);
            dot += __shfl_xor(dot, 32);
            float mu  = sum * 0.03125f;
            float var = fmaf(-mu, mu, ss * 0.03125f);
            float inv = rsqrtf(var + 1e-3f);
            float res = fmaf(inv, fmaf(-mu, G, dot), C);
            if (half == 0) lout[(b0 + u) * 5 + w] = res;
        }
        {
            float sum = 0.f, ss = 0.f, dot = 0.f;
            #pragma unroll
            for (int r = 0; r < 16; ++r) {
                float e = elu1(accB[r]);
                sum += e;
                ss  = fmaf(e, e, ss);
                dot = fmaf(e, g2r[r], dot);
            }
            sum += __shfl_xor(sum, 32);
            ss  += __shfl_xor(ss, 32);
            dot += __shfl_xor(dot, 32);
            float mu  = sum * 0.03125f;
            float var = fmaf(-mu, mu, ss * 0.03125f);
            float inv = rsqrtf(var + 1e-3f);
            float res = fmaf(inv, fmaf(-mu, G, dot), C);
            if (half == 0) lout[(b0 + 32 + u) * 5 + w] = res;
        }

        // ---- write panel it+1 from the pending regs (compiler emits
        //      vmcnt(2): waits the OLDER pair, newest 2 stay in flight) ----
        if (it < 7) {
            *(short4*)&xs[nxt][srow0 * XS_STRIDE + schk * 4] = cvt4(p0);
            *(short4*)&xs[nxt][srow1 * XS_STRIDE + schk * 4] = cvt4(p1);
            barrier_ds_only();   // DS visibility only; vmcnt NOT drained
        }

        p0 = f0;
        p1 = f1;
    }

    __syncthreads();   // final full barrier before the gather

    // ---- gather/store: 512 rows, 2 per thread, float4 each (write-exact) ----
    {
        const int r0 = tid;
        const int r1 = tid + 256;
        float4 o0, o1;
        o0.x = lout[r0 * 5 + 0]; o0.y = lout[r0 * 5 + 1];
        o0.z = lout[r0 * 5 + 2]; o0.w = lout[r0 * 5 + 3];
        o1.x = lout[r1 * 5 + 0]; o1.y = lout[r1 * 5 + 1];
        o1.z = lout[r1 * 5 + 2]; o1.w = lout[r1 * 5 + 3];
        *(float4*)(out + (size_t)(band + r0) * 128 + qt * 4) = o0;
        *(float4*)(out + (size_t)(band + r1) * 128 + qt * 4) = o1;
    }
}

extern "C" void kernel_launch(void* const* d_in, const int* in_sizes, int n_in,
                              void* d_out, int out_size, void* d_ws, size_t ws_size,
                              hipStream_t stream) {
    const float* x     = (const float*)d_in[0];
    const float* W1    = (const float*)d_in[1];
    const float* b1    = (const float*)d_in[2];
    const float* gamma = (const float*)d_in[3];
    const float* beta  = (const float*)d_in[4];
    const float* W2    = (const float*)d_in[5];
    const float* b2    = (const float*)d_in[6];
    float* out = (float*)d_out;

    dim3 grid(32, 32);   // (512-row bands, q-tiles of 4)
    divenc_mfma<<<grid, 256, 0, stream>>>(x, W1, b1, gamma, beta, W2, b2, out);
}